// Round 16
// baseline (437.464 us; speedup 1.0000x reference)
//
#include <hip/hip_runtime.h>
#include <hip/hip_fp16.h>
#include <math.h>

// ---------------------------------------------------------------------------
// PNA (2 conv layers) on MI355X.
//   pre:  [A|B] = x @ [Wl|Wr]^T (+b on B)   (single-product fp16 MFMA)
//   CSR build: hist -> scan(+avglog) -> 2-level bucket sort
//   gathers: 1 node/wave, 2 feats/lane x 2 edge-groups (h=lane>>5),
//            8 packed loads in flight = 16 rows; masked 2-edge tail
//   aggr: stored as single fp16
//   post1: single-product fp16 MFMA GEMM, fragment-major fp16 weights,
//          LDS double-buffered weight staging via global_load_lds
//   fused_conv2: gather + 2-col dot (no aggr materialization)
// ---------------------------------------------------------------------------

typedef __attribute__((ext_vector_type(4))) float f32x4;
typedef __attribute__((ext_vector_type(8))) _Float16 f16x8;

#define AS1 __attribute__((address_space(1)))
#define AS3 __attribute__((address_space(3)))
__device__ inline void gload16(const void* g, void* l) {
  __builtin_amdgcn_global_load_lds((AS1 const void*)g, (AS3 void*)l, 16, 0, 0);
}

__device__ inline unsigned pkmax16(unsigned a, unsigned b) {
  unsigned r;
  asm("v_pk_max_f16 %0, %1, %2" : "=v"(r) : "v"(a), "v"(b));
  return r;
}
__device__ inline unsigned pkmin16(unsigned a, unsigned b) {
  unsigned r;
  asm("v_pk_min_f16 %0, %1, %2" : "=v"(r) : "v"(a), "v"(b));
  return r;
}

#define ME_S0 (64 * 832)
#define ME_S1 (ME_S0 + 64)
#define ME_S2 (ME_S1 + 2 * 832)
#define ME_S3 (ME_S2 + 2)
#define ME_S4 (ME_S3 + 128 * 64)
#define ME_S5 (ME_S4 + 128 * 64)

__global__ void make_eff_kernel(const float* __restrict__ W1_post, const float* __restrict__ b1_post,
                                const float* __restrict__ W1_lin, const float* __restrict__ b1_lin,
                                const float* __restrict__ W2_post, const float* __restrict__ b2_post,
                                const float* __restrict__ W2_lin, const float* __restrict__ b2_lin,
                                const float* __restrict__ W1_pre, const float* __restrict__ W2_pre,
                                __half* __restrict__ W1f,
                                float* __restrict__ b1eff,
                                float* __restrict__ W2eff, float* __restrict__ b2eff,
                                __half* __restrict__ Wp1f, __half* __restrict__ Wp2f) {
  int id = blockIdx.x * blockDim.x + threadIdx.x;
  if (id < ME_S0) {
    int o = id / 832, k = id - o * 832;
    float s = 0.f;
#pragma unroll 8
    for (int j = 0; j < 64; ++j) s = fmaf(W1_lin[o * 64 + j], W1_post[j * 832 + k], s);
    // fragment-major layout: lane = klg*16 + ar holds elems j for (col, k)
    int q = k >> 5, klg = (k >> 3) & 3, jj = k & 7;
    int ct = o >> 4, ar = o & 15;
    int idx = ((q * 4 + ct) * 64 + (klg * 16 + ar)) * 8 + jj;
    W1f[idx] = __float2half(s);
  } else if (id < ME_S1) {
    int o = id - ME_S0;
    float s = b1_lin[o];
    for (int j = 0; j < 64; ++j) s = fmaf(W1_lin[o * 64 + j], b1_post[j], s);
    b1eff[o] = s;
  } else if (id < ME_S2) {
    int t = id - ME_S1;
    int o = t / 832, k = t - o * 832;
    W2eff[t] = fmaf(W2_lin[o * 2 + 0], W2_post[k], W2_lin[o * 2 + 1] * W2_post[832 + k]);
  } else if (id < ME_S3) {
    int o = id - ME_S2;
    b2eff[o] = b2_lin[o] + W2_lin[o * 2 + 0] * b2_post[0] + W2_lin[o * 2 + 1] * b2_post[1];
  } else if (id < ME_S4) {
    int t = id - ME_S3;
    int c = t >> 6, k = t & 63;
    float v = (c < 64) ? W1_pre[c * 128 + k] : W1_pre[(c - 64) * 128 + 64 + k];
    Wp1f[t] = __float2half(v);
  } else if (id < ME_S5) {
    int t = id - ME_S4;
    int c = t >> 6, k = t & 63;
    float v = (c < 64) ? W2_pre[c * 128 + k] : W2_pre[(c - 64) * 128 + 64 + k];
    Wp2f[t] = __float2half(v);
  }
}

__global__ void hist_kernel(const int* __restrict__ dst, int* __restrict__ deg, int E) {
  int i = blockIdx.x * blockDim.x + threadIdx.x;
  if (i < E) atomicAdd(&deg[dst[i]], 1);
}

// scan1 + avglog fused
__global__ void scan1_kernel(const int* __restrict__ deg, int* __restrict__ excl,
                             int* __restrict__ partial, float* __restrict__ avgsum, int n) {
  __shared__ int wsums[4];
  __shared__ float red[4];
  int tid = threadIdx.x, b = blockIdx.x;
  int i = b * 256 + tid;
  int lane = tid & 63, wid = tid >> 6;
  int v = (i < n) ? deg[i] : 0;
  float lg = (i < n) ? logf((float)v + 1.0f) : 0.0f;
  for (int off = 32; off; off >>= 1) lg += __shfl_down(lg, off);
  if (lane == 0) red[wid] = lg;
  int x = v;
  for (int off = 1; off < 64; off <<= 1) {
    int t = __shfl_up(x, off);
    if (lane >= off) x += t;
  }
  if (lane == 63) wsums[wid] = x;
  __syncthreads();
  int wo = 0;
#pragma unroll
  for (int j = 0; j < 4; ++j) wo += (j < wid) ? wsums[j] : 0;
  if (i < n) excl[i] = wo + x - v;
  if (tid == 255) partial[b] = wo + x;
  if (tid == 0) atomicAdd(avgsum, red[0] + red[1] + red[2] + red[3]);
}

__global__ void scan2_kernel(int* __restrict__ partial, int nb) {
  __shared__ int wsums[16];
  int tid = threadIdx.x;
  int lane = tid & 63, wid = tid >> 6;
  int v = (tid < nb) ? partial[tid] : 0;
  int x = v;
  for (int off = 1; off < 64; off <<= 1) {
    int t = __shfl_up(x, off);
    if (lane >= off) x += t;
  }
  if (lane == 63) wsums[wid] = x;
  __syncthreads();
  if (wid == 0) {
    int w2 = (lane < 16) ? wsums[lane] : 0;
    for (int off = 1; off < 16; off <<= 1) {
      int t = __shfl_up(w2, off);
      if (lane >= off) w2 += t;
    }
    if (lane < 16) wsums[lane] = w2;
  }
  __syncthreads();
  int wo = (wid > 0) ? wsums[wid - 1] : 0;
  if (tid < nb) partial[tid] = wo + x - v;
}

// scan3 + bucket_init fused
__global__ void scan3_kernel(const int* __restrict__ deg, const int* __restrict__ excl,
                             const int* __restrict__ partial, int* __restrict__ rowptr,
                             int* __restrict__ cursor, int* __restrict__ bcur,
                             float* __restrict__ amp, float* __restrict__ inv,
                             const float* __restrict__ avgsum, int n, int E) {
  int i = blockIdx.x * 256 + threadIdx.x;
  if (i < n) {
    int r = excl[i] + partial[blockIdx.x];
    rowptr[i] = r;
    cursor[i] = r;
    if ((i & 1023) == 0) bcur[i >> 10] = r;
    int v = deg[i];
    float dnm = (float)(v > 0 ? v : 1);
    float a = logf(dnm + 1.0f) * ((float)n / avgsum[0]);
    amp[i] = a;
    inv[i] = 1.0f / a;
  }
  if (i == 0) rowptr[n] = E;
}

// ---- 2-level bucket sort CSR build (bucket = 1024 dst nodes) ----
#define BMAX 104
#define BINCAP 72
#define ACHUNK 4096

__global__ __launch_bounds__(256) void bucket_scatter(
    const int* __restrict__ src, const int* __restrict__ dst,
    int* __restrict__ bcur, int2* __restrict__ bmaj, int E, int nbuk) {
  __shared__ int bin_cnt[BMAX];
  __shared__ int bin_len[BMAX];
  __shared__ int bin_base[BMAX];
  __shared__ int bin_pref[BMAX + 1];
  __shared__ int2 bin_buf[BMAX * BINCAP];
  int tid = threadIdx.x;
  for (int b = tid; b < BMAX; b += 256) bin_cnt[b] = 0;
  __syncthreads();
  int start = blockIdx.x * ACHUNK;
  int end = start + ACHUNK;
  if (end > E) end = E;
  for (int i = start + tid; i < end; i += 256) {
    int s = src[i], d = dst[i];
    int b = d >> 10;
    int slot = atomicAdd(&bin_cnt[b], 1);
    if (slot < BINCAP) {
      bin_buf[b * BINCAP + slot] = make_int2(s, d);
    } else {
      int pos = atomicAdd(&bcur[b], 1);
      bmaj[pos] = make_int2(s, d);
    }
  }
  __syncthreads();
  if (tid < nbuk) {
    int c = bin_cnt[tid];
    bin_len[tid] = (c < BINCAP) ? c : BINCAP;
  }
  __syncthreads();
  if (tid == 0) {
    int acc = 0;
    for (int b = 0; b < nbuk; ++b) {
      bin_pref[b] = acc;
      acc += bin_len[b];
    }
    bin_pref[nbuk] = acc;
  }
  __syncthreads();
  if (tid < nbuk && bin_len[tid] > 0) bin_base[tid] = atomicAdd(&bcur[tid], bin_len[tid]);
  __syncthreads();
  int T = bin_pref[nbuk];
  for (int t = tid; t < T; t += 256) {
    int lo = 0, hi = nbuk - 1;
    while (lo < hi) {
      int mid = (lo + hi + 1) >> 1;
      if (bin_pref[mid] <= t) lo = mid; else hi = mid - 1;
    }
    int j = t - bin_pref[lo];
    bmaj[bin_base[lo] + j] = bin_buf[lo * BINCAP + j];
  }
}

__global__ __launch_bounds__(1024) void bucket_fill(
    const int2* __restrict__ bmaj, const int* __restrict__ rowptr,
    int* __restrict__ cursor, int* __restrict__ col, int n, int E) {
  int b = blockIdx.x;
  int i0 = b << 10;
  int i1 = i0 + 1024;
  if (i0 > n) i0 = n;
  if (i1 > n) i1 = n;
  int start = rowptr[i0];
  int end = rowptr[i1];
  for (int e = start + (int)threadIdx.x; e < end; e += 1024) {
    int2 p = bmaj[e];
    int pos = atomicAdd(&cursor[p.y], 1);
    col[pos] = p.x;
  }
}

// [A|B] = x @ [Wl|Wr]^T, bias folded into B (B stored fp16).
// Single-product fp16 MFMA, 128-row blocks.
__global__ __launch_bounds__(256, 2) void pre_mfma(
    const float* __restrict__ xin, const __half* __restrict__ Wpf,
    const float* __restrict__ bias,
    float* __restrict__ A, __half* __restrict__ Bo, int n) {
  __shared__ __attribute__((aligned(16))) __half XF[128 * 64];
  int tid = threadIdx.x;
  int lane = tid & 63, w = tid >> 6;
  int row0 = blockIdx.x * 128;
  int sr = tid >> 1, hf = tid & 1;
  int grow = row0 + sr;
  {
    _Float16 hs[32];
    if (grow < n) {
      const float4* p = (const float4*)(xin + (size_t)grow * 64 + hf * 32);
#pragma unroll
      for (int q = 0; q < 8; ++q) {
        float4 t = p[q];
        hs[q * 4 + 0] = (_Float16)t.x; hs[q * 4 + 1] = (_Float16)t.y;
        hs[q * 4 + 2] = (_Float16)t.z; hs[q * 4 + 3] = (_Float16)t.w;
      }
    } else {
#pragma unroll
      for (int j = 0; j < 32; ++j) hs[j] = (_Float16)0.f;
    }
    int rsw = sr & 7;
#pragma unroll
    for (int q = 0; q < 4; ++q) {
      int g = hf * 4 + q;
      int off = sr * 64 + ((g ^ rsw) << 3);
      *(f16x8*)&XF[off] = *(const f16x8*)&hs[q * 8];
    }
  }
  __syncthreads();
  int ar = lane & 15, klg = lane >> 4;
  f32x4 acc[2][8];
#pragma unroll
  for (int rf = 0; rf < 2; ++rf)
#pragma unroll
    for (int ct = 0; ct < 8; ++ct) acc[rf][ct] = (f32x4){0.f, 0.f, 0.f, 0.f};
#pragma unroll
  for (int kk = 0; kk < 64; kk += 32) {
    f16x8 ah[2];
#pragma unroll
    for (int rf = 0; rf < 2; ++rf) {
      int lrow = w * 32 + rf * 16 + ar;
      int g = (kk >> 3) + klg;
      int off = lrow * 64 + ((g ^ (lrow & 7)) << 3);
      ah[rf] = *(const f16x8*)&XF[off];
    }
    int ko = kk + klg * 8;
#pragma unroll
    for (int ct = 0; ct < 8; ++ct) {
      size_t br = (size_t)(ct * 16 + ar) * 64 + ko;
      f16x8 bw = *(const f16x8*)&Wpf[br];
#pragma unroll
      for (int rf = 0; rf < 2; ++rf)
        acc[rf][ct] = __builtin_amdgcn_mfma_f32_16x16x32_f16(ah[rf], bw, acc[rf][ct], 0, 0, 0);
    }
  }
#pragma unroll
  for (int rf = 0; rf < 2; ++rf)
#pragma unroll
    for (int i = 0; i < 4; ++i) {
      int r = row0 + w * 32 + rf * 16 + klg * 4 + i;
      if (r < n) {
#pragma unroll
        for (int ct = 0; ct < 8; ++ct) {
          int c = ct * 16 + ar;
          float vv = acc[rf][ct][i];
          if (ct < 4) A[(size_t)r * 64 + c] = vv;
          else Bo[(size_t)r * 64 + (c - 64)] = __float2half(vv + bias[c - 64]);
        }
      }
    }
}

// ---- packed gather: 1 node/wave, h=lane>>5 edge-group, fl=lane&31 feat pair.
// Main loop: 16 edges (8 per group, 8 loads in flight = 16 rows).
// Tail: masked 2-edge steps. Cross-group combine via shfl_xor(32).
#define PROC2(vv)                                                           \
  { float2 f = __half22float2(*(__half2*)&(vv));                            \
    sum.x += f.x; sum.y += f.y;                                             \
    sq.x = fmaf(f.x, f.x, sq.x); sq.y = fmaf(f.y, f.y, sq.y);               \
    mxp = pkmax16(mxp, (vv)); mnp = pkmin16(mnp, (vv)); }

#define GATHER_STATS2                                                       \
  int h = lane >> 5, fl = lane & 31;                                        \
  float2 sum = make_float2(0.f, 0.f), sq = make_float2(0.f, 0.f);           \
  unsigned mxp = 0xFC00FC00u, mnp = 0x7C007C00u;                            \
  int e = s0;                                                               \
  for (; e + 16 <= s1; e += 16) {                                           \
    int base = e + h * 8;                                                   \
    int idx[8];                                                             \
    _Pragma("unroll") for (int j = 0; j < 8; ++j) idx[j] = col[base + j];   \
    unsigned v[8];                                                          \
    _Pragma("unroll") for (int j = 0; j < 8; ++j)                           \
        v[j] = *(const unsigned*)&B[(size_t)idx[j] * 64 + fl * 2];          \
    _Pragma("unroll") for (int j = 0; j < 8; ++j) PROC2(v[j])               \
  }                                                                         \
  for (; e < s1; e += 2) {                                                  \
    int ei = e + h;                                                         \
    bool valid = ei < s1;                                                   \
    int c = col[valid ? ei : (s1 - 1)];                                     \
    unsigned v = *(const unsigned*)&B[(size_t)c * 64 + fl * 2];             \
    if (valid) PROC2(v)                                                     \
  }                                                                         \
  sum.x += __shfl_xor(sum.x, 32); sum.y += __shfl_xor(sum.y, 32);           \
  sq.x += __shfl_xor(sq.x, 32);  sq.y += __shfl_xor(sq.y, 32);              \
  { unsigned u;                                                             \
    u = (unsigned)__shfl_xor((int)mxp, 32); mxp = pkmax16(mxp, u);          \
    u = (unsigned)__shfl_xor((int)mnp, 32); mnp = pkmin16(mnp, u); }

// finalize: st0=mean, st1=min, st2=max, st3=std (float2 over feats 2fl,2fl+1)
#define FINALIZE2                                                           \
  float2 st0, st1, st2, st3;                                                \
  {                                                                         \
    int d = s1 - s0;                                                        \
    if (d > 0) {                                                            \
      float idn = 1.0f / (float)d;                                          \
      float2 a2 = *(const float2*)&A[(size_t)node * 64 + fl * 2];           \
      float2 mnf = __half22float2(*(__half2*)&mnp);                         \
      float2 mxf = __half22float2(*(__half2*)&mxp);                         \
      float mbx = sum.x * idn, mby = sum.y * idn;                           \
      st0 = make_float2(a2.x + mbx, a2.y + mby);                            \
      st1 = make_float2(a2.x + mnf.x, a2.y + mnf.y);                        \
      st2 = make_float2(a2.x + mxf.x, a2.y + mxf.y);                        \
      st3 = make_float2(                                                    \
          sqrtf(fmaxf(fmaf(-mbx, mbx, sq.x * idn), 0.f) + 1e-5f),           \
          sqrtf(fmaxf(fmaf(-mby, mby, sq.y * idn), 0.f) + 1e-5f));          \
    } else {                                                                \
      st0 = make_float2(0.f, 0.f); st1 = st0; st2 = st0;                    \
      float s = sqrtf(1e-5f);                                               \
      st3 = make_float2(s, s);                                              \
    }                                                                       \
  }

__device__ __forceinline__ void agg_write2(__half* __restrict__ AggF, size_t o, float2 v) {
  unsigned hp = (unsigned)__half_as_ushort(__float2half(v.x)) |
                ((unsigned)__half_as_ushort(__float2half(v.y)) << 16);
  *(unsigned*)&AggF[o] = hp;
}

// wave per node: packed gather stats -> fp16 Agg
__global__ __launch_bounds__(256) void aggr_pack(
    const float* __restrict__ A, const __half* __restrict__ B,
    const int* __restrict__ rowptr, const int* __restrict__ col,
    __half* __restrict__ AggF, int n) {
  int tid = threadIdx.x;
  int lane = tid & 63, wv = tid >> 6;
  int node = blockIdx.x * 4 + wv;
  if (node >= n) return;
  int s0 = rowptr[node], s1 = rowptr[node + 1];
  GATHER_STATS2
  FINALIZE2
  if (h == 0) {
    size_t o = (size_t)node * 256 + fl * 2;
    agg_write2(AggF, o, st0);
    agg_write2(AggF, o + 64, st1);
    agg_write2(AggF, o + 128, st2);
    agg_write2(AggF, o + 192, st3);
  }
}

// post1: single-product fp16 MFMA GEMM. 128-row blocks, 4 waves x 32 rows.
// fp16 fragment-major weights streamed through LDS, 13 double-buffered chunks.
__global__ __launch_bounds__(256) void post1_kernel(
    const float* __restrict__ x, const __half* __restrict__ AggF,
    const float* __restrict__ amp, const float* __restrict__ inv,
    const __half* __restrict__ Wf, const float* __restrict__ beff,
    float* __restrict__ h1, int n) {
  __shared__ __attribute__((aligned(16))) __half WS[8192];  // 2 x 4096 halfs
  int tid = threadIdx.x;
  int lane = tid & 63, w = tid >> 6;
  int row0 = blockIdx.x * 128;
  int ar = lane & 15, klg = lane >> 4;
  int grow[2];
  bool rok[2];
#pragma unroll
  for (int rf = 0; rf < 2; ++rf) {
    grow[rf] = row0 + w * 32 + rf * 16 + ar;
    rok[rf] = grow[rf] < n;
  }
  f32x4 accP[2][4], accQ[2][4], accR[2][4];
#pragma unroll
  for (int rf = 0; rf < 2; ++rf)
#pragma unroll
    for (int ct = 0; ct < 4; ++ct) {
      accP[rf][ct] = (f32x4){0.f, 0.f, 0.f, 0.f};
      accQ[rf][ct] = (f32x4){0.f, 0.f, 0.f, 0.f};
      accR[rf][ct] = (f32x4){0.f, 0.f, 0.f, 0.f};
    }

  auto stage = [&](int c, int buf) {
    const __half* srcbase = Wf + c * 4096;
    __half* dstbase = &WS[buf * 4096];
#pragma unroll
    for (int i = 0; i < 2; ++i) {
      int boff = w * 1024 + i * 512 + lane * 8;
      gload16(srcbase + boff, dstbase + boff);
    }
  };

  stage(0, 0);
  __syncthreads();

#pragma unroll
  for (int cidx = 0; cidx < 13; ++cidx) {
    int cur = cidx & 1;
    if (cidx + 1 < 13) stage(cidx + 1, cur ^ 1);
    const __half* Wc = &WS[cur * 4096];
    if (cidx == 0) {
#pragma unroll
      for (int l = 0; l < 2; ++l) {
        f16x8 ah[2];
#pragma unroll
        for (int rf = 0; rf < 2; ++rf) {
          _Float16 hs[8];
          if (rok[rf]) {
            const float* p = x + (size_t)grow[rf] * 64 + l * 32 + klg * 8;
            float4 v0 = *(const float4*)p;
            float4 v1 = *(const float4*)(p + 4);
            hs[0] = (_Float16)v0.x; hs[1] = (_Float16)v0.y;
            hs[2] = (_Float16)v0.z; hs[3] = (_Float16)v0.w;
            hs[4] = (_Float16)v1.x; hs[5] = (_Float16)v1.y;
            hs[6] = (_Float16)v1.z; hs[7] = (_Float16)v1.w;
          } else {
#pragma unroll
            for (int j = 0; j < 8; ++j) hs[j] = (_Float16)0.f;
          }
          ah[rf] = *(const f16x8*)hs;
        }
#pragma unroll
        for (int ct = 0; ct < 4; ++ct) {
          int fo = ((l * 4 + ct) * 64 + lane) * 8;
          f16x8 bw = *(const f16x8*)&Wc[fo];
#pragma unroll
          for (int rf = 0; rf < 2; ++rf)
            accP[rf][ct] = __builtin_amdgcn_mfma_f32_16x16x32_f16(ah[rf], bw, accP[rf][ct], 0, 0, 0);
        }
      }
    } else {
      int str = (cidx - 1) >> 2;  // compile-time after unroll
      int cc = (cidx - 1) & 3;
#pragma unroll
      for (int l = 0; l < 2; ++l) {
        f16x8 ah[2];
#pragma unroll
        for (int rf = 0; rf < 2; ++rf) {
          if (rok[rf]) {
            size_t ao = (size_t)grow[rf] * 256 + cc * 64 + l * 32 + klg * 8;
            ah[rf] = *(const f16x8*)&AggF[ao];
          } else {
            _Float16 z[8] = {};
            ah[rf] = *(const f16x8*)z;
          }
        }
        auto do_mfma = [&](f32x4 (&acc)[2][4]) {
#pragma unroll
          for (int ct = 0; ct < 4; ++ct) {
            int fo = ((l * 4 + ct) * 64 + lane) * 8;
            f16x8 bw = *(const f16x8*)&Wc[fo];
#pragma unroll
            for (int rf = 0; rf < 2; ++rf)
              acc[rf][ct] = __builtin_amdgcn_mfma_f32_16x16x32_f16(ah[rf], bw, acc[rf][ct], 0, 0, 0);
          }
        };
        if (str == 0) do_mfma(accP);
        else if (str == 1) do_mfma(accQ);
        else do_mfma(accR);
      }
    }
    __syncthreads();
  }
#pragma unroll
  for (int rf = 0; rf < 2; ++rf)
#pragma unroll
    for (int i = 0; i < 4; ++i) {
      int r = row0 + w * 32 + rf * 16 + klg * 4 + i;
      if (r < n) {
        float av = amp[r], iv = inv[r];
#pragma unroll
        for (int ct = 0; ct < 4; ++ct) {
          int colo = ct * 16 + ar;
          float vv = accP[rf][ct][i] + av * accQ[rf][ct][i] + iv * accR[rf][ct][i] + beff[colo];
          h1[(size_t)r * 64 + colo] = fmaxf(vv, 0.f);
        }
      }
    }
}

// fused conv2: packed gather + 2-col dot (float2 per lane), 32-lane reduce
__global__ __launch_bounds__(256) void fused_conv2(
    const float* __restrict__ h1, const float* __restrict__ A,
    const __half* __restrict__ B, const int* __restrict__ rowptr,
    const int* __restrict__ col, const float* __restrict__ amp,
    const float* __restrict__ inv, const float* __restrict__ W2eff,
    const float* __restrict__ b2eff, float* __restrict__ out, int n) {
  int tid = threadIdx.x;
  int lane = tid & 63, wv = tid >> 6;
  int node = blockIdx.x * 4 + wv;
  if (node >= n) return;
  int s0 = rowptr[node], s1 = rowptr[node + 1];
  GATHER_STATS2
  FINALIZE2
  float av = amp[node], iv = inv[node];
  float2 xv = *(const float2*)&h1[(size_t)node * 64 + fl * 2];
  const float* W0 = W2eff;
  const float* W1 = W2eff + 832;
  float2 wx0 = *(const float2*)&W0[fl * 2];
  float2 wx1 = *(const float2*)&W1[fl * 2];
  float p0 = wx0.x * xv.x + wx0.y * xv.y;
  float p1 = wx1.x * xv.x + wx1.y * xv.y;
#define DOT_STAT2(ST, C)                                                      \
  {                                                                           \
    int jj = 64 + (C)*64 + fl * 2;                                            \
    float2 a0 = *(const float2*)&W0[jj];                                      \
    float2 b0 = *(const float2*)&W0[jj + 256];                                \
    float2 c0 = *(const float2*)&W0[jj + 512];                                \
    float2 a1 = *(const float2*)&W1[jj];                                      \
    float2 b1 = *(const float2*)&W1[jj + 256];                                \
    float2 c1 = *(const float2*)&W1[jj + 512];                                \
    p0 += ST.x * fmaf(av, b0.x, fmaf(iv, c0.x, a0.x))                         \
        + ST.y * fmaf(av, b0.y, fmaf(iv, c0.y, a0.y));                        \
    p1 += ST.x * fmaf(av, b1.x, fmaf(iv, c1.x, a1.x))                         \
        + ST.y * fmaf(av, b1.y, fmaf(iv, c1.y, a1.y));                        \
  }
  DOT_STAT2(st0, 0)
  DOT_STAT2(st1, 1)
  DOT_STAT2(st2, 2)
  DOT_STAT2(st3, 3)
#undef DOT_STAT2
#pragma unroll
  for (int m = 1; m <= 16; m <<= 1) {
    p0 += __shfl_xor(p0, m);
    p1 += __shfl_xor(p1, m);
  }
  if (lane == 0) {
    out[(size_t)node * 2 + 0] = p0 + b2eff[0];
    out[(size_t)node * 2 + 1] = p1 + b2eff[1];
  }
}

extern "C" void kernel_launch(void* const* d_in, const int* in_sizes, int n_in,
                              void* d_out, int out_size, void* d_ws, size_t ws_size,
                              hipStream_t stream) {
  const float* x = (const float*)d_in[0];
  const int* ei = (const int*)d_in[1];
  const float* W1_pre = (const float*)d_in[2];
  const float* b1_pre = (const float*)d_in[3];
  const float* W1_post = (const float*)d_in[4];
  const float* b1_post = (const float*)d_in[5];
  const float* W1_lin = (const float*)d_in[6];
  const float* b1_lin = (const float*)d_in[7];
  const float* W2_pre = (const float*)d_in[8];
  const float* b2_pre = (const float*)d_in[9];
  const float* W2_post = (const float*)d_in[10];
  const float* b2_post = (const float*)d_in[11];
  const float* W2_lin = (const float*)d_in[12];
  const float* b2_lin = (const float*)d_in[13];

  const int N = in_sizes[0] / 64;
  const int E = in_sizes[1] / 2;
  const int* srcp = ei;
  const int* dstp = ei + E;
  const int nb = (N + 255) / 256;
  const int nbuk = (N + 1023) >> 10;

  char* ws = (char*)d_ws;
  size_t off = 0;
  auto take = [&](size_t bytes) -> void* {
    void* p = ws + off;
    off = (off + bytes + 255) & ~(size_t)255;
    return p;
  };
  int* deg = (int*)take((size_t)N * 4);
  int* rowptr = (int*)take((size_t)(N + 1) * 4);
  int* cursor = (int*)take((size_t)N * 4);
  int* tmp = (int*)take((size_t)N * 4);
  int* partial = (int*)take(4096);
  int* bcur = (int*)take(4096);
  float* amp = (float*)take((size_t)N * 4);
  float* inv = (float*)take((size_t)N * 4);
  float* avgsum = (float*)take(4);
  __half* W1f = (__half*)take((size_t)64 * 832 * 2);
  float* b1eff = (float*)take(64 * 4);
  float* W2eff = (float*)take((size_t)2 * 832 * 4);
  float* b2eff = (float*)take(2 * 4);
  __half* Wp1f = (__half*)take((size_t)128 * 64 * 2);
  __half* Wp2f = (__half*)take((size_t)128 * 64 * 2);
  int* col = (int*)take((size_t)E * 4);
  int2* bmaj = (int2*)take((size_t)E * 8);
  float* Abuf = (float*)take((size_t)N * 64 * 4);
  __half* Bbuf = (__half*)take((size_t)N * 64 * 2);
  __half* AggF = (__half*)take((size_t)N * 256 * 2);
  float* h1 = (float*)take((size_t)N * 64 * 4);
  (void)ws_size; (void)n_in; (void)out_size;

  hipMemsetAsync(deg, 0, (size_t)N * 4, stream);
  hipMemsetAsync(avgsum, 0, 4, stream);

  make_eff_kernel<<<(ME_S5 + 255) / 256, 256, 0, stream>>>(
      W1_post, b1_post, W1_lin, b1_lin, W2_post, b2_post, W2_lin, b2_lin,
      W1_pre, W2_pre, W1f, b1eff, W2eff, b2eff, Wp1f, Wp2f);
  hist_kernel<<<(E + 255) / 256, 256, 0, stream>>>(dstp, deg, E);
  scan1_kernel<<<nb, 256, 0, stream>>>(deg, tmp, partial, avgsum, N);
  scan2_kernel<<<1, 1024, 0, stream>>>(partial, nb);
  scan3_kernel<<<nb, 256, 0, stream>>>(deg, tmp, partial, rowptr, cursor, bcur,
                                       amp, inv, avgsum, N, E);
  bucket_scatter<<<(E + ACHUNK - 1) / ACHUNK, 256, 0, stream>>>(srcp, dstp, bcur, bmaj, E, nbuk);
  bucket_fill<<<nbuk, 1024, 0, stream>>>(bmaj, rowptr, cursor, col, N, E);

  // conv1
  pre_mfma<<<(N + 127) / 128, 256, 0, stream>>>(x, Wp1f, b1_pre, Abuf, Bbuf, N);
  aggr_pack<<<(N + 3) / 4, 256, 0, stream>>>(Abuf, Bbuf, rowptr, col, AggF, N);
  post1_kernel<<<(N + 127) / 128, 256, 0, stream>>>(x, AggF, amp, inv, W1f, b1eff, h1, N);
  // conv2
  pre_mfma<<<(N + 127) / 128, 256, 0, stream>>>(h1, Wp2f, b2_pre, Abuf, Bbuf, N);
  fused_conv2<<<(N + 3) / 4, 256, 0, stream>>>(h1, Abuf, Bbuf, rowptr, col, amp, inv,
                                               W2eff, b2eff, (float*)d_out, N);
}

// Round 17
// 377.193 us; speedup vs baseline: 1.1598x; 1.1598x over previous
//
#include <hip/hip_runtime.h>
#include <hip/hip_fp16.h>
#include <math.h>

// ---------------------------------------------------------------------------
// PNA (2 conv layers) on MI355X.  (R15 configuration — empirical optimum.)
//   pre:  [A|B] = x @ [Wl|Wr]^T (+b on B)   (single-product fp16 MFMA)
//   CSR build: hist -> scan(+avglog) -> 2-level bucket sort
//   gathers: 1 node/wave, lane=feat, fp16 B, 16-deep scalar pipeline
//            (PROVEN optimal: 16 in-flight load instrs/wave; see R7/R12/R14/R16)
//   aggr: stored as single fp16
//   post1: single-product fp16 MFMA GEMM, fragment-major fp16 weights,
//          LDS double-buffered weight staging via global_load_lds
//   fused_conv2: gather + 2-col dot (no aggr materialization)
// ---------------------------------------------------------------------------

typedef __attribute__((ext_vector_type(4))) float f32x4;
typedef __attribute__((ext_vector_type(8))) _Float16 f16x8;

#define AS1 __attribute__((address_space(1)))
#define AS3 __attribute__((address_space(3)))
__device__ inline void gload16(const void* g, void* l) {
  __builtin_amdgcn_global_load_lds((AS1 const void*)g, (AS3 void*)l, 16, 0, 0);
}

#define ME_S0 (64 * 832)
#define ME_S1 (ME_S0 + 64)
#define ME_S2 (ME_S1 + 2 * 832)
#define ME_S3 (ME_S2 + 2)
#define ME_S4 (ME_S3 + 128 * 64)
#define ME_S5 (ME_S4 + 128 * 64)

__global__ void make_eff_kernel(const float* __restrict__ W1_post, const float* __restrict__ b1_post,
                                const float* __restrict__ W1_lin, const float* __restrict__ b1_lin,
                                const float* __restrict__ W2_post, const float* __restrict__ b2_post,
                                const float* __restrict__ W2_lin, const float* __restrict__ b2_lin,
                                const float* __restrict__ W1_pre, const float* __restrict__ W2_pre,
                                __half* __restrict__ W1f,
                                float* __restrict__ b1eff,
                                float* __restrict__ W2eff, float* __restrict__ b2eff,
                                __half* __restrict__ Wp1f, __half* __restrict__ Wp2f) {
  int id = blockIdx.x * blockDim.x + threadIdx.x;
  if (id < ME_S0) {
    int o = id / 832, k = id - o * 832;
    float s = 0.f;
#pragma unroll 8
    for (int j = 0; j < 64; ++j) s = fmaf(W1_lin[o * 64 + j], W1_post[j * 832 + k], s);
    // fragment-major layout: lane = klg*16 + ar holds elems j for (col, k)
    int q = k >> 5, klg = (k >> 3) & 3, jj = k & 7;
    int ct = o >> 4, ar = o & 15;
    int idx = ((q * 4 + ct) * 64 + (klg * 16 + ar)) * 8 + jj;
    W1f[idx] = __float2half(s);
  } else if (id < ME_S1) {
    int o = id - ME_S0;
    float s = b1_lin[o];
    for (int j = 0; j < 64; ++j) s = fmaf(W1_lin[o * 64 + j], b1_post[j], s);
    b1eff[o] = s;
  } else if (id < ME_S2) {
    int t = id - ME_S1;
    int o = t / 832, k = t - o * 832;
    W2eff[t] = fmaf(W2_lin[o * 2 + 0], W2_post[k], W2_lin[o * 2 + 1] * W2_post[832 + k]);
  } else if (id < ME_S3) {
    int o = id - ME_S2;
    b2eff[o] = b2_lin[o] + W2_lin[o * 2 + 0] * b2_post[0] + W2_lin[o * 2 + 1] * b2_post[1];
  } else if (id < ME_S4) {
    int t = id - ME_S3;
    int c = t >> 6, k = t & 63;
    float v = (c < 64) ? W1_pre[c * 128 + k] : W1_pre[(c - 64) * 128 + 64 + k];
    Wp1f[t] = __float2half(v);
  } else if (id < ME_S5) {
    int t = id - ME_S4;
    int c = t >> 6, k = t & 63;
    float v = (c < 64) ? W2_pre[c * 128 + k] : W2_pre[(c - 64) * 128 + 64 + k];
    Wp2f[t] = __float2half(v);
  }
}

__global__ void hist_kernel(const int* __restrict__ dst, int* __restrict__ deg, int E) {
  int i = blockIdx.x * blockDim.x + threadIdx.x;
  if (i < E) atomicAdd(&deg[dst[i]], 1);
}

// scan1 + avglog fused: per-block exclusive scan partials + log-degree sum
__global__ void scan1_kernel(const int* __restrict__ deg, int* __restrict__ excl,
                             int* __restrict__ partial, float* __restrict__ avgsum, int n) {
  __shared__ int wsums[4];
  __shared__ float red[4];
  int tid = threadIdx.x, b = blockIdx.x;
  int i = b * 256 + tid;
  int lane = tid & 63, wid = tid >> 6;
  int v = (i < n) ? deg[i] : 0;
  float lg = (i < n) ? logf((float)v + 1.0f) : 0.0f;
  for (int off = 32; off; off >>= 1) lg += __shfl_down(lg, off);
  if (lane == 0) red[wid] = lg;
  int x = v;
  for (int off = 1; off < 64; off <<= 1) {
    int t = __shfl_up(x, off);
    if (lane >= off) x += t;
  }
  if (lane == 63) wsums[wid] = x;
  __syncthreads();
  int wo = 0;
#pragma unroll
  for (int j = 0; j < 4; ++j) wo += (j < wid) ? wsums[j] : 0;
  if (i < n) excl[i] = wo + x - v;
  if (tid == 255) partial[b] = wo + x;
  if (tid == 0) atomicAdd(avgsum, red[0] + red[1] + red[2] + red[3]);
}

__global__ void scan2_kernel(int* __restrict__ partial, int nb) {
  __shared__ int wsums[16];
  int tid = threadIdx.x;
  int lane = tid & 63, wid = tid >> 6;
  int v = (tid < nb) ? partial[tid] : 0;
  int x = v;
  for (int off = 1; off < 64; off <<= 1) {
    int t = __shfl_up(x, off);
    if (lane >= off) x += t;
  }
  if (lane == 63) wsums[wid] = x;
  __syncthreads();
  if (wid == 0) {
    int w2 = (lane < 16) ? wsums[lane] : 0;
    for (int off = 1; off < 16; off <<= 1) {
      int t = __shfl_up(w2, off);
      if (lane >= off) w2 += t;
    }
    if (lane < 16) wsums[lane] = w2;
  }
  __syncthreads();
  int wo = (wid > 0) ? wsums[wid - 1] : 0;
  if (tid < nb) partial[tid] = wo + x - v;
}

// scan3 + bucket_init fused
__global__ void scan3_kernel(const int* __restrict__ deg, const int* __restrict__ excl,
                             const int* __restrict__ partial, int* __restrict__ rowptr,
                             int* __restrict__ cursor, int* __restrict__ bcur,
                             float* __restrict__ amp, float* __restrict__ inv,
                             const float* __restrict__ avgsum, int n, int E) {
  int i = blockIdx.x * 256 + threadIdx.x;
  if (i < n) {
    int r = excl[i] + partial[blockIdx.x];
    rowptr[i] = r;
    cursor[i] = r;
    if ((i & 1023) == 0) bcur[i >> 10] = r;
    int v = deg[i];
    float dnm = (float)(v > 0 ? v : 1);
    float a = logf(dnm + 1.0f) * ((float)n / avgsum[0]);
    amp[i] = a;
    inv[i] = 1.0f / a;
  }
  if (i == 0) rowptr[n] = E;
}

// ---- 2-level bucket sort CSR build (bucket = 1024 dst nodes) ----
#define BMAX 104
#define BINCAP 72
#define ACHUNK 4096

__global__ __launch_bounds__(256) void bucket_scatter(
    const int* __restrict__ src, const int* __restrict__ dst,
    int* __restrict__ bcur, int2* __restrict__ bmaj, int E, int nbuk) {
  __shared__ int bin_cnt[BMAX];
  __shared__ int bin_len[BMAX];
  __shared__ int bin_base[BMAX];
  __shared__ int bin_pref[BMAX + 1];
  __shared__ int2 bin_buf[BMAX * BINCAP];
  int tid = threadIdx.x;
  for (int b = tid; b < BMAX; b += 256) bin_cnt[b] = 0;
  __syncthreads();
  int start = blockIdx.x * ACHUNK;
  int end = start + ACHUNK;
  if (end > E) end = E;
  for (int i = start + tid; i < end; i += 256) {
    int s = src[i], d = dst[i];
    int b = d >> 10;
    int slot = atomicAdd(&bin_cnt[b], 1);
    if (slot < BINCAP) {
      bin_buf[b * BINCAP + slot] = make_int2(s, d);
    } else {
      int pos = atomicAdd(&bcur[b], 1);
      bmaj[pos] = make_int2(s, d);
    }
  }
  __syncthreads();
  if (tid < nbuk) {
    int c = bin_cnt[tid];
    bin_len[tid] = (c < BINCAP) ? c : BINCAP;
  }
  __syncthreads();
  if (tid == 0) {
    int acc = 0;
    for (int b = 0; b < nbuk; ++b) {
      bin_pref[b] = acc;
      acc += bin_len[b];
    }
    bin_pref[nbuk] = acc;
  }
  __syncthreads();
  if (tid < nbuk && bin_len[tid] > 0) bin_base[tid] = atomicAdd(&bcur[tid], bin_len[tid]);
  __syncthreads();
  int T = bin_pref[nbuk];
  for (int t = tid; t < T; t += 256) {
    int lo = 0, hi = nbuk - 1;
    while (lo < hi) {
      int mid = (lo + hi + 1) >> 1;
      if (bin_pref[mid] <= t) lo = mid; else hi = mid - 1;
    }
    int j = t - bin_pref[lo];
    bmaj[bin_base[lo] + j] = bin_buf[lo * BINCAP + j];
  }
}

__global__ __launch_bounds__(1024) void bucket_fill(
    const int2* __restrict__ bmaj, const int* __restrict__ rowptr,
    int* __restrict__ cursor, int* __restrict__ col, int n, int E) {
  int b = blockIdx.x;
  int i0 = b << 10;
  int i1 = i0 + 1024;
  if (i0 > n) i0 = n;
  if (i1 > n) i1 = n;
  int start = rowptr[i0];
  int end = rowptr[i1];
  for (int e = start + (int)threadIdx.x; e < end; e += 1024) {
    int2 p = bmaj[e];
    int pos = atomicAdd(&cursor[p.y], 1);
    col[pos] = p.x;
  }
}

// [A|B] = x @ [Wl|Wr]^T, bias folded into B (B stored fp16).
// Single-product fp16 MFMA, 128-row blocks.
__global__ __launch_bounds__(256, 2) void pre_mfma(
    const float* __restrict__ xin, const __half* __restrict__ Wpf,
    const float* __restrict__ bias,
    float* __restrict__ A, __half* __restrict__ Bo, int n) {
  __shared__ __attribute__((aligned(16))) __half XF[128 * 64];
  int tid = threadIdx.x;
  int lane = tid & 63, w = tid >> 6;
  int row0 = blockIdx.x * 128;
  int sr = tid >> 1, hf = tid & 1;
  int grow = row0 + sr;
  {
    _Float16 hs[32];
    if (grow < n) {
      const float4* p = (const float4*)(xin + (size_t)grow * 64 + hf * 32);
#pragma unroll
      for (int q = 0; q < 8; ++q) {
        float4 t = p[q];
        hs[q * 4 + 0] = (_Float16)t.x; hs[q * 4 + 1] = (_Float16)t.y;
        hs[q * 4 + 2] = (_Float16)t.z; hs[q * 4 + 3] = (_Float16)t.w;
      }
    } else {
#pragma unroll
      for (int j = 0; j < 32; ++j) hs[j] = (_Float16)0.f;
    }
    int rsw = sr & 7;
#pragma unroll
    for (int q = 0; q < 4; ++q) {
      int g = hf * 4 + q;
      int off = sr * 64 + ((g ^ rsw) << 3);
      *(f16x8*)&XF[off] = *(const f16x8*)&hs[q * 8];
    }
  }
  __syncthreads();
  int ar = lane & 15, klg = lane >> 4;
  f32x4 acc[2][8];
#pragma unroll
  for (int rf = 0; rf < 2; ++rf)
#pragma unroll
    for (int ct = 0; ct < 8; ++ct) acc[rf][ct] = (f32x4){0.f, 0.f, 0.f, 0.f};
#pragma unroll
  for (int kk = 0; kk < 64; kk += 32) {
    f16x8 ah[2];
#pragma unroll
    for (int rf = 0; rf < 2; ++rf) {
      int lrow = w * 32 + rf * 16 + ar;
      int g = (kk >> 3) + klg;
      int off = lrow * 64 + ((g ^ (lrow & 7)) << 3);
      ah[rf] = *(const f16x8*)&XF[off];
    }
    int ko = kk + klg * 8;
#pragma unroll
    for (int ct = 0; ct < 8; ++ct) {
      size_t br = (size_t)(ct * 16 + ar) * 64 + ko;
      f16x8 bw = *(const f16x8*)&Wpf[br];
#pragma unroll
      for (int rf = 0; rf < 2; ++rf)
        acc[rf][ct] = __builtin_amdgcn_mfma_f32_16x16x32_f16(ah[rf], bw, acc[rf][ct], 0, 0, 0);
    }
  }
#pragma unroll
  for (int rf = 0; rf < 2; ++rf)
#pragma unroll
    for (int i = 0; i < 4; ++i) {
      int r = row0 + w * 32 + rf * 16 + klg * 4 + i;
      if (r < n) {
#pragma unroll
        for (int ct = 0; ct < 8; ++ct) {
          int c = ct * 16 + ar;
          float vv = acc[rf][ct][i];
          if (ct < 4) A[(size_t)r * 64 + c] = vv;
          else Bo[(size_t)r * 64 + (c - 64)] = __float2half(vv + bias[c - 64]);
        }
      }
    }
}

// ---- shared gather macro body: 1 node/wave, lane=feat, fp16 B, 16-deep ----
#define GATHER_STATS                                                        \
  float sum = 0.f, sq = 0.f, mx = -3.4e38f, mn = 3.4e38f;                   \
  int e = s0;                                                               \
  for (; e + 16 <= s1; e += 16) {                                           \
    int idx[16];                                                            \
    _Pragma("unroll") for (int j = 0; j < 16; ++j) idx[j] = col[e + j];     \
    __half hv[16];                                                          \
    _Pragma("unroll") for (int j = 0; j < 16; ++j)                          \
        hv[j] = B[(size_t)idx[j] * 64 + lane];                              \
    _Pragma("unroll") for (int j = 0; j < 16; ++j) {                        \
      float b = __half2float(hv[j]);                                        \
      sum += b; sq = fmaf(b, b, sq);                                        \
      mx = fmaxf(mx, b); mn = fminf(mn, b);                                 \
    }                                                                       \
  }                                                                         \
  for (; e + 4 <= s1; e += 4) {                                             \
    int idx[4];                                                             \
    _Pragma("unroll") for (int j = 0; j < 4; ++j) idx[j] = col[e + j];      \
    __half hv[4];                                                           \
    _Pragma("unroll") for (int j = 0; j < 4; ++j)                           \
        hv[j] = B[(size_t)idx[j] * 64 + lane];                              \
    _Pragma("unroll") for (int j = 0; j < 4; ++j) {                         \
      float b = __half2float(hv[j]);                                        \
      sum += b; sq = fmaf(b, b, sq);                                        \
      mx = fmaxf(mx, b); mn = fminf(mn, b);                                 \
    }                                                                       \
  }                                                                         \
  for (; e < s1; ++e) {                                                     \
    float b = __half2float(B[(size_t)col[e] * 64 + lane]);                  \
    sum += b; sq = fmaf(b, b, sq);                                          \
    mx = fmaxf(mx, b); mn = fminf(mn, b);                                   \
  }

// wave per node: CSR gather stats of fp16 B -> fp16 Agg
__global__ __launch_bounds__(256) void aggr_pack(
    const float* __restrict__ A, const __half* __restrict__ B,
    const int* __restrict__ rowptr, const int* __restrict__ col,
    __half* __restrict__ AggF, int n) {
  int tid = threadIdx.x;
  int lane = tid & 63, wv = tid >> 6;
  int node = blockIdx.x * 4 + wv;
  if (node >= n) return;
  int s0 = rowptr[node], s1 = rowptr[node + 1];
  GATHER_STATS
  int d = s1 - s0;
  float st[4];
  if (d > 0) {
    float idn = 1.0f / (float)d;
    float mB = sum * idn;
    float a = A[(size_t)node * 64 + lane];
    st[0] = a + mB;
    st[1] = a + mn;
    st[2] = a + mx;
    float var = fmaf(-mB, mB, sq * idn);
    st[3] = sqrtf(fmaxf(var, 0.0f) + 1e-5f);
  } else {
    st[0] = 0.f; st[1] = 0.f; st[2] = 0.f; st[3] = sqrtf(1e-5f);
  }
  size_t o = (size_t)node * 256 + lane;
#pragma unroll
  for (int c = 0; c < 4; ++c) AggF[o + c * 64] = __float2half(st[c]);
}

// post1: single-product fp16 MFMA GEMM. 128-row blocks, 4 waves x 32 rows.
// fp16 fragment-major weights streamed through LDS, 13 double-buffered chunks.
__global__ __launch_bounds__(256) void post1_kernel(
    const float* __restrict__ x, const __half* __restrict__ AggF,
    const float* __restrict__ amp, const float* __restrict__ inv,
    const __half* __restrict__ Wf, const float* __restrict__ beff,
    float* __restrict__ h1, int n) {
  __shared__ __attribute__((aligned(16))) __half WS[8192];  // 2 x 4096 halfs
  int tid = threadIdx.x;
  int lane = tid & 63, w = tid >> 6;
  int row0 = blockIdx.x * 128;
  int ar = lane & 15, klg = lane >> 4;
  int grow[2];
  bool rok[2];
#pragma unroll
  for (int rf = 0; rf < 2; ++rf) {
    grow[rf] = row0 + w * 32 + rf * 16 + ar;
    rok[rf] = grow[rf] < n;
  }
  f32x4 accP[2][4], accQ[2][4], accR[2][4];
#pragma unroll
  for (int rf = 0; rf < 2; ++rf)
#pragma unroll
    for (int ct = 0; ct < 4; ++ct) {
      accP[rf][ct] = (f32x4){0.f, 0.f, 0.f, 0.f};
      accQ[rf][ct] = (f32x4){0.f, 0.f, 0.f, 0.f};
      accR[rf][ct] = (f32x4){0.f, 0.f, 0.f, 0.f};
    }

  auto stage = [&](int c, int buf) {
    const __half* srcbase = Wf + c * 4096;
    __half* dstbase = &WS[buf * 4096];
#pragma unroll
    for (int i = 0; i < 2; ++i) {
      int boff = w * 1024 + i * 512 + lane * 8;
      gload16(srcbase + boff, dstbase + boff);
    }
  };

  stage(0, 0);
  __syncthreads();

#pragma unroll
  for (int cidx = 0; cidx < 13; ++cidx) {
    int cur = cidx & 1;
    if (cidx + 1 < 13) stage(cidx + 1, cur ^ 1);
    const __half* Wc = &WS[cur * 4096];
    if (cidx == 0) {
#pragma unroll
      for (int l = 0; l < 2; ++l) {
        f16x8 ah[2];
#pragma unroll
        for (int rf = 0; rf < 2; ++rf) {
          _Float16 hs[8];
          if (rok[rf]) {
            const float* p = x + (size_t)grow[rf] * 64 + l * 32 + klg * 8;
            float4 v0 = *(const float4*)p;
            float4 v1 = *(const float4*)(p + 4);
            hs[0] = (_Float16)v0.x; hs[1] = (_Float16)v0.y;
            hs[2] = (_Float16)v0.z; hs[3] = (_Float16)v0.w;
            hs[4] = (_Float16)v1.x; hs[5] = (_Float16)v1.y;
            hs[6] = (_Float16)v1.z; hs[7] = (_Float16)v1.w;
          } else {
#pragma unroll
            for (int j = 0; j < 8; ++j) hs[j] = (_Float16)0.f;
          }
          ah[rf] = *(const f16x8*)hs;
        }
#pragma unroll
        for (int ct = 0; ct < 4; ++ct) {
          int fo = ((l * 4 + ct) * 64 + lane) * 8;
          f16x8 bw = *(const f16x8*)&Wc[fo];
#pragma unroll
          for (int rf = 0; rf < 2; ++rf)
            accP[rf][ct] = __builtin_amdgcn_mfma_f32_16x16x32_f16(ah[rf], bw, accP[rf][ct], 0, 0, 0);
        }
      }
    } else {
      int str = (cidx - 1) >> 2;  // compile-time after unroll
      int cc = (cidx - 1) & 3;
#pragma unroll
      for (int l = 0; l < 2; ++l) {
        f16x8 ah[2];
#pragma unroll
        for (int rf = 0; rf < 2; ++rf) {
          if (rok[rf]) {
            size_t ao = (size_t)grow[rf] * 256 + cc * 64 + l * 32 + klg * 8;
            ah[rf] = *(const f16x8*)&AggF[ao];
          } else {
            _Float16 z[8] = {};
            ah[rf] = *(const f16x8*)z;
          }
        }
        auto do_mfma = [&](f32x4 (&acc)[2][4]) {
#pragma unroll
          for (int ct = 0; ct < 4; ++ct) {
            int fo = ((l * 4 + ct) * 64 + lane) * 8;
            f16x8 bw = *(const f16x8*)&Wc[fo];
#pragma unroll
            for (int rf = 0; rf < 2; ++rf)
              acc[rf][ct] = __builtin_amdgcn_mfma_f32_16x16x32_f16(ah[rf], bw, acc[rf][ct], 0, 0, 0);
          }
        };
        if (str == 0) do_mfma(accP);
        else if (str == 1) do_mfma(accQ);
        else do_mfma(accR);
      }
    }
    __syncthreads();
  }
#pragma unroll
  for (int rf = 0; rf < 2; ++rf)
#pragma unroll
    for (int i = 0; i < 4; ++i) {
      int r = row0 + w * 32 + rf * 16 + klg * 4 + i;
      if (r < n) {
        float av = amp[r], iv = inv[r];
#pragma unroll
        for (int ct = 0; ct < 4; ++ct) {
          int colo = ct * 16 + ar;
          float vv = accP[rf][ct][i] + av * accQ[rf][ct][i] + iv * accR[rf][ct][i] + beff[colo];
          h1[(size_t)r * 64 + colo] = fmaxf(vv, 0.f);
        }
      }
    }
}

// fused conv2: wave/node stats + 2-col dot, wave reduce
__global__ __launch_bounds__(256) void fused_conv2(
    const float* __restrict__ h1, const float* __restrict__ A,
    const __half* __restrict__ B, const int* __restrict__ rowptr,
    const int* __restrict__ col, const float* __restrict__ amp,
    const float* __restrict__ inv, const float* __restrict__ W2eff,
    const float* __restrict__ b2eff, float* __restrict__ out, int n) {
  int tid = threadIdx.x;
  int lane = tid & 63, wv = tid >> 6;
  int node = blockIdx.x * 4 + wv;
  if (node >= n) return;
  int s0 = rowptr[node], s1 = rowptr[node + 1];
  GATHER_STATS
  int d = s1 - s0;
  float st[4];
  if (d > 0) {
    float idn = 1.0f / (float)d;
    float mB = sum * idn;
    float a = A[(size_t)node * 64 + lane];
    st[0] = a + mB;
    st[1] = a + mn;
    st[2] = a + mx;
    float var = fmaf(-mB, mB, sq * idn);
    st[3] = sqrtf(fmaxf(var, 0.0f) + 1e-5f);
  } else {
    st[0] = 0.f; st[1] = 0.f; st[2] = 0.f; st[3] = sqrtf(1e-5f);
  }
  float av = amp[node], iv = inv[node];
  float xv = h1[(size_t)node * 64 + lane];
  float p0 = W2eff[lane] * xv;
  float p1 = W2eff[832 + lane] * xv;
#pragma unroll
  for (int m = 0; m < 4; ++m) {
    int j = m * 64 + lane;
    p0 = fmaf(st[m], fmaf(av, W2eff[320 + j], fmaf(iv, W2eff[576 + j], W2eff[64 + j])), p0);
    p1 = fmaf(st[m], fmaf(av, W2eff[832 + 320 + j], fmaf(iv, W2eff[832 + 576 + j], W2eff[832 + 64 + j])), p1);
  }
#pragma unroll
  for (int m = 32; m; m >>= 1) {
    p0 += __shfl_xor(p0, m);
    p1 += __shfl_xor(p1, m);
  }
  if (lane == 0) {
    out[(size_t)node * 2 + 0] = p0 + b2eff[0];
    out[(size_t)node * 2 + 1] = p1 + b2eff[1];
  }
}

extern "C" void kernel_launch(void* const* d_in, const int* in_sizes, int n_in,
                              void* d_out, int out_size, void* d_ws, size_t ws_size,
                              hipStream_t stream) {
  const float* x = (const float*)d_in[0];
  const int* ei = (const int*)d_in[1];
  const float* W1_pre = (const float*)d_in[2];
  const float* b1_pre = (const float*)d_in[3];
  const float* W1_post = (const float*)d_in[4];
  const float* b1_post = (const float*)d_in[5];
  const float* W1_lin = (const float*)d_in[6];
  const float* b1_lin = (const float*)d_in[7];
  const float* W2_pre = (const float*)d_in[8];
  const float* b2_pre = (const float*)d_in[9];
  const float* W2_post = (const float*)d_in[10];
  const float* b2_post = (const float*)d_in[11];
  const float* W2_lin = (const float*)d_in[12];
  const float* b2_lin = (const float*)d_in[13];

  const int N = in_sizes[0] / 64;
  const int E = in_sizes[1] / 2;
  const int* srcp = ei;
  const int* dstp = ei + E;
  const int nb = (N + 255) / 256;
  const int nbuk = (N + 1023) >> 10;

  char* ws = (char*)d_ws;
  size_t off = 0;
  auto take = [&](size_t bytes) -> void* {
    void* p = ws + off;
    off = (off + bytes + 255) & ~(size_t)255;
    return p;
  };
  int* deg = (int*)take((size_t)N * 4);
  int* rowptr = (int*)take((size_t)(N + 1) * 4);
  int* cursor = (int*)take((size_t)N * 4);
  int* tmp = (int*)take((size_t)N * 4);
  int* partial = (int*)take(4096);
  int* bcur = (int*)take(4096);
  float* amp = (float*)take((size_t)N * 4);
  float* inv = (float*)take((size_t)N * 4);
  float* avgsum = (float*)take(4);
  __half* W1f = (__half*)take((size_t)64 * 832 * 2);
  float* b1eff = (float*)take(64 * 4);
  float* W2eff = (float*)take((size_t)2 * 832 * 4);
  float* b2eff = (float*)take(2 * 4);
  __half* Wp1f = (__half*)take((size_t)128 * 64 * 2);
  __half* Wp2f = (__half*)take((size_t)128 * 64 * 2);
  int* col = (int*)take((size_t)E * 4);
  int2* bmaj = (int2*)take((size_t)E * 8);
  float* Abuf = (float*)take((size_t)N * 64 * 4);
  __half* Bbuf = (__half*)take((size_t)N * 64 * 2);
  __half* AggF = (__half*)take((size_t)N * 256 * 2);
  float* h1 = (float*)take((size_t)N * 64 * 4);
  (void)ws_size; (void)n_in; (void)out_size;

  hipMemsetAsync(deg, 0, (size_t)N * 4, stream);
  hipMemsetAsync(avgsum, 0, 4, stream);

  make_eff_kernel<<<(ME_S5 + 255) / 256, 256, 0, stream>>>(
      W1_post, b1_post, W1_lin, b1_lin, W2_post, b2_post, W2_lin, b2_lin,
      W1_pre, W2_pre, W1f, b1eff, W2eff, b2eff, Wp1f, Wp2f);
  hist_kernel<<<(E + 255) / 256, 256, 0, stream>>>(dstp, deg, E);
  scan1_kernel<<<nb, 256, 0, stream>>>(deg, tmp, partial, avgsum, N);
  scan2_kernel<<<1, 1024, 0, stream>>>(partial, nb);
  scan3_kernel<<<nb, 256, 0, stream>>>(deg, tmp, partial, rowptr, cursor, bcur,
                                       amp, inv, avgsum, N, E);
  bucket_scatter<<<(E + ACHUNK - 1) / ACHUNK, 256, 0, stream>>>(srcp, dstp, bcur, bmaj, E, nbuk);
  bucket_fill<<<nbuk, 1024, 0, stream>>>(bmaj, rowptr, cursor, col, N, E);

  // conv1
  pre_mfma<<<(N + 127) / 128, 256, 0, stream>>>(x, Wp1f, b1_pre, Abuf, Bbuf, N);
  aggr_pack<<<(N + 3) / 4, 256, 0, stream>>>(Abuf, Bbuf, rowptr, col, AggF, N);
  post1_kernel<<<(N + 127) / 128, 256, 0, stream>>>(x, AggF, amp, inv, W1f, b1eff, h1, N);
  // conv2
  pre_mfma<<<(N + 127) / 128, 256, 0, stream>>>(h1, Wp2f, b2_pre, Abuf, Bbuf, N);
  fused_conv2<<<(N + 3) / 4, 256, 0, stream>>>(h1, Abuf, Bbuf, rowptr, col, amp, inv,
                                               W2eff, b2eff, (float*)d_out, N);
}